// Round 1
// baseline (570.413 us; speedup 1.0000x reference)
//
#include <hip/hip_runtime.h>
#include <hip/hip_bf16.h>

#define NODES 32768
#define HD 128
#define NE 524288
#define NR 8

typedef unsigned int u32;

// ---- ws byte offsets ----
#define X0_OFF   (0u)
#define X1_OFF   (16u<<20)
#define S_OFF    (32u<<20)   // bf16, 64 MB
#define ADJ_OFF  (96u<<20)   // u32 x NE
#define RP_OFF   (99u<<20)   // u32 x (NODES+1)
#define CUR_OFF  (100u<<20)  // u32 x NODES
#define BSUM_OFF (101u<<20)  // u32 x 128

__device__ __forceinline__ float bflo(u32 u){ union{u32 i;float f;}c; c.i=u<<16; return c.f; }
__device__ __forceinline__ float bfhi(u32 u){ union{u32 i;float f;}c; c.i=u&0xffff0000u; return c.f; }

__device__ __forceinline__ void fma64(const float* At, const float* Wt,
                                      int mq, int gq, float acc[8][4])
{
#pragma unroll 8
  for(int kk=0;kk<64;kk++){
    const float4 a0=*(const float4*)&At[kk*68+mq*8];
    const float4 a1=*(const float4*)&At[kk*68+mq*8+4];
    const float4 w =*(const float4*)&Wt[kk*132+gq*4];
    float av[8]={a0.x,a0.y,a0.z,a0.w,a1.x,a1.y,a1.z,a1.w};
#pragma unroll
    for(int i=0;i<8;i++){
      acc[i][0]=fmaf(av[i],w.x,acc[i][0]);
      acc[i][1]=fmaf(av[i],w.y,acc[i][1]);
      acc[i][2]=fmaf(av[i],w.z,acc[i][2]);
      acc[i][3]=fmaf(av[i],w.w,acc[i][3]);
    }
  }
}

// ---------------- embed + projection GEMM: x0 = (cemb[cid]+kemb[kid]) @ pW^T + pb ----
__global__ __launch_bounds__(256) void embed_gemm(
    const int* __restrict__ cid, const int* __restrict__ kid,
    const float* __restrict__ cemb, const float* __restrict__ kemb,
    const float* __restrict__ pW, const float* __restrict__ pb,
    float* __restrict__ xo)
{
  __shared__ float At[64*68];
  __shared__ float Wt[64*132];
  const int tid=threadIdx.x;
  const int d0=blockIdx.x*64;
  const int mq=tid>>5, gq=tid&31;
  float acc[8][4];
#pragma unroll
  for(int i=0;i<8;i++){ acc[i][0]=0.f; acc[i][1]=0.f; acc[i][2]=0.f; acc[i][3]=0.f; }

  for(int c=0;c<2;c++){
    const int h0=c*64;
    __syncthreads();
    { int m=tid>>2; int hh=(tid&3)*16;
      int ci=cid[d0+m], ki=kid[d0+m];
      const float* cp=cemb+(size_t)ci*HD+h0+hh;
      const float* kp=kemb+(size_t)ki*HD+h0+hh;
      float* ap=&At[hh*68+m];
#pragma unroll
      for(int j=0;j<16;j+=4){
        float4 a=*(const float4*)(cp+j);
        float4 b=*(const float4*)(kp+j);
        ap[(j+0)*68]=a.x+b.x; ap[(j+1)*68]=a.y+b.y;
        ap[(j+2)*68]=a.z+b.z; ap[(j+3)*68]=a.w+b.w;
      }
    }
    { int g=tid>>1; int hh=(tid&1)*32;
      const float* wp=pW+(size_t)g*HD+h0+hh;
      float* wl=&Wt[hh*132+g];
#pragma unroll
      for(int j=0;j<32;j+=4){
        float4 w=*(const float4*)(wp+j);
        wl[(j+0)*132]=w.x; wl[(j+1)*132]=w.y; wl[(j+2)*132]=w.z; wl[(j+3)*132]=w.w;
      }
    }
    __syncthreads();
    fma64(At,Wt,mq,gq,acc);
  }
  const float4 bias=*(const float4*)&pb[gq*4];
#pragma unroll
  for(int i=0;i<8;i++){
    float4 o;
    o.x=acc[i][0]+bias.x; o.y=acc[i][1]+bias.y;
    o.z=acc[i][2]+bias.z; o.w=acc[i][3]+bias.w;
    *(float4*)&xo[(size_t)(d0+mq*8+i)*HD+gq*4]=o;
  }
}

// ---------------- CSR build ----------------
__global__ void count_deg(const int* __restrict__ dst, u32* __restrict__ cnt){
  int e=blockIdx.x*256+threadIdx.x;
  atomicAdd(&cnt[dst[e]],1u);
}

__global__ void scan1(const u32* __restrict__ cnt, u32* __restrict__ rp, u32* __restrict__ bsum){
  __shared__ u32 sh[256];
  int t=threadIdx.x; int base=blockIdx.x*256;
  u32 v=cnt[base+t]; sh[t]=v; __syncthreads();
  for(int off=1;off<256;off<<=1){
    u32 tv=(t>=off)?sh[t-off]:0u; __syncthreads();
    sh[t]+=tv; __syncthreads();
  }
  rp[base+t]=sh[t]-v;
  if(t==255) bsum[blockIdx.x]=sh[255];
}

__global__ void scan2(u32* __restrict__ bsum, u32* __restrict__ rp){
  __shared__ u32 sh[128];
  int t=threadIdx.x;
  u32 v=bsum[t]; sh[t]=v; __syncthreads();
  for(int off=1;off<128;off<<=1){
    u32 tv=(t>=off)?sh[t-off]:0u; __syncthreads();
    sh[t]+=tv; __syncthreads();
  }
  bsum[t]=sh[t]-v;
  if(t==0) rp[NODES]=NE;
}

__global__ void scan3(u32* __restrict__ rp, const u32* __restrict__ bsum){
  int i=blockIdx.x*256+threadIdx.x;
  rp[i]+=bsum[blockIdx.x];
}

__global__ void scatter_edges(const int* __restrict__ src, const int* __restrict__ dst,
                              const int* __restrict__ et, const u32* __restrict__ rp,
                              u32* __restrict__ cur, u32* __restrict__ adj){
  int e=blockIdx.x*256+threadIdx.x;
  int d=dst[e];
  u32 pos=atomicAdd(&cur[d],1u);
  adj[rp[d]+pos]=(u32)src[e] | ((u32)et[e]<<16);
}

// ---------------- phase A: S[d][r][:] = sum of x[src] over in-edges of type r ----
__global__ __launch_bounds__(256) void phase_a(
    const float* __restrict__ x, const u32* __restrict__ adj,
    const u32* __restrict__ rp, __hip_bfloat16* __restrict__ S)
{
  __shared__ float sacc[4][NR*HD];
  const int w=threadIdx.x>>6, lane=threadIdx.x&63;
  const int d=blockIdx.x*4+w;
  for(int i=lane;i<NR*HD;i+=64) sacc[w][i]=0.f;
  __syncthreads();
  const int beg=(int)rp[d], end=(int)rp[d+1];
  for(int e=beg;e<end;++e){
    u32 a=adj[e];
    int srcn=(int)(a&0xffffu); int t=(int)(a>>16);
    float2 v=*(const float2*)&x[(size_t)srcn*HD+2*lane];
    float* p=&sacc[w][t*HD+2*lane];
    p[0]+=v.x; p[1]+=v.y;
  }
  __syncthreads();
  __hip_bfloat16* so=S+(size_t)d*(NR*HD);
  for(int i=0;i<16;i++){
    int k=i*64+lane;
    so[k]=__float2bfloat16(sacc[w][k]);
  }
}

// ---------------- layer GEMM: xo = relu( x@selfW^T + b + (S@Wcat)/deg ) [* mask] ----
__global__ __launch_bounds__(256) void layer_gemm(
    const float* __restrict__ x, const __hip_bfloat16* __restrict__ S,
    const float* __restrict__ relW, const float* __restrict__ selfW,
    const float* __restrict__ selfb, const u32* __restrict__ rp,
    const int* __restrict__ mask, float* __restrict__ xo, int last)
{
  __shared__ float At[64*68];
  __shared__ float Wt[64*132];
  const int tid=threadIdx.x, d0=blockIdx.x*64;
  const int mq=tid>>5, gq=tid&31;
  float acc[8][4];
#pragma unroll
  for(int i=0;i<8;i++){ acc[i][0]=0.f; acc[i][1]=0.f; acc[i][2]=0.f; acc[i][3]=0.f; }

  // message region: K = 1024 (8 relations x 128), 16 chunks of 64
  for(int c=0;c<16;c++){
    __syncthreads();
    { int m=tid>>2; int ks=(tid&3)*16;
      const unsigned short* sp=(const unsigned short*)S+(size_t)(d0+m)*(NR*HD)+c*64+ks;
      uint4 u0=*(const uint4*)sp;
      uint4 u1=*(const uint4*)(sp+8);
      float* ap=&At[ks*68+m];
      ap[0*68]=bflo(u0.x);  ap[1*68]=bfhi(u0.x);
      ap[2*68]=bflo(u0.y);  ap[3*68]=bfhi(u0.y);
      ap[4*68]=bflo(u0.z);  ap[5*68]=bfhi(u0.z);
      ap[6*68]=bflo(u0.w);  ap[7*68]=bfhi(u0.w);
      ap[8*68]=bflo(u1.x);  ap[9*68]=bfhi(u1.x);
      ap[10*68]=bflo(u1.y); ap[11*68]=bfhi(u1.y);
      ap[12*68]=bflo(u1.z); ap[13*68]=bfhi(u1.z);
      ap[14*68]=bflo(u1.w); ap[15*68]=bfhi(u1.w);
    }
    { int g=tid>>1; int hh=(tid&1)*32;
      const float* wp=relW+((size_t)(c>>1)*HD+g)*HD+(c&1)*64+hh;
      float* wl=&Wt[hh*132+g];
#pragma unroll
      for(int j=0;j<32;j+=4){
        float4 w=*(const float4*)(wp+j);
        wl[(j+0)*132]=w.x; wl[(j+1)*132]=w.y; wl[(j+2)*132]=w.z; wl[(j+3)*132]=w.w;
      }
    }
    __syncthreads();
    fma64(At,Wt,mq,gq,acc);
  }

  // scale message accumulators by 1/deg
#pragma unroll
  for(int i=0;i<8;i++){
    int d=d0+mq*8+i;
    float dg=(float)(rp[d+1]-rp[d]);
    dg=fmaxf(dg,1.f);
    float inv=1.f/dg;
    acc[i][0]*=inv; acc[i][1]*=inv; acc[i][2]*=inv; acc[i][3]*=inv;
  }

  // self region: K = 128, 2 chunks of 64
  for(int c=0;c<2;c++){
    __syncthreads();
    { int m=tid>>2; int ks=(tid&3)*16;
      const float* xp=x+(size_t)(d0+m)*HD+c*64+ks;
      float* ap=&At[ks*68+m];
#pragma unroll
      for(int j=0;j<16;j+=4){
        float4 a=*(const float4*)(xp+j);
        ap[(j+0)*68]=a.x; ap[(j+1)*68]=a.y; ap[(j+2)*68]=a.z; ap[(j+3)*68]=a.w;
      }
    }
    { int g=tid>>1; int hh=(tid&1)*32;
      const float* wp=selfW+(size_t)g*HD+c*64+hh;
      float* wl=&Wt[hh*132+g];
#pragma unroll
      for(int j=0;j<32;j+=4){
        float4 w=*(const float4*)(wp+j);
        wl[(j+0)*132]=w.x; wl[(j+1)*132]=w.y; wl[(j+2)*132]=w.z; wl[(j+3)*132]=w.w;
      }
    }
    __syncthreads();
    fma64(At,Wt,mq,gq,acc);
  }

  const float4 bias=*(const float4*)&selfb[gq*4];
#pragma unroll
  for(int i=0;i<8;i++){
    int m=d0+mq*8+i;
    float mk = last ? (float)mask[m] : 1.f;
    float4 o;
    o.x=fmaxf(acc[i][0]+bias.x,0.f)*mk;
    o.y=fmaxf(acc[i][1]+bias.y,0.f)*mk;
    o.z=fmaxf(acc[i][2]+bias.z,0.f)*mk;
    o.w=fmaxf(acc[i][3]+bias.w,0.f)*mk;
    *(float4*)&xo[(size_t)m*HD+gq*4]=o;
  }
}

extern "C" void kernel_launch(void* const* d_in, const int* in_sizes, int n_in,
                              void* d_out, int out_size, void* d_ws, size_t ws_size,
                              hipStream_t stream)
{
  (void)in_sizes; (void)n_in; (void)out_size; (void)ws_size;
  const int*   cid =(const int*)  d_in[0];
  const int*   kid =(const int*)  d_in[1];
  const int*   mask=(const int*)  d_in[2];
  const int*   ei  =(const int*)  d_in[3];
  const int*   et  =(const int*)  d_in[4];
  const float* cemb=(const float*)d_in[5];
  const float* kemb=(const float*)d_in[6];
  const float* pW  =(const float*)d_in[7];
  const float* pb  =(const float*)d_in[8];
  const float* sW  =(const float*)d_in[9];
  const float* sb  =(const float*)d_in[10];
  const float* rW  =(const float*)d_in[11];
  float* out=(float*)d_out;
  char*  ws =(char*)d_ws;

  float* x0=(float*)(ws+X0_OFF);
  float* x1=(float*)(ws+X1_OFF);
  __hip_bfloat16* S=(__hip_bfloat16*)(ws+S_OFF);
  u32* adj =(u32*)(ws+ADJ_OFF);
  u32* rp  =(u32*)(ws+RP_OFF);
  u32* cur =(u32*)(ws+CUR_OFF);
  u32* bsum=(u32*)(ws+BSUM_OFF);
  const int* srcA=ei;
  const int* dstA=ei+NE;

  hipMemsetAsync(cur,0,NODES*sizeof(u32),stream);
  embed_gemm<<<NODES/64,256,0,stream>>>(cid,kid,cemb,kemb,pW,pb,x0);
  count_deg<<<NE/256,256,0,stream>>>(dstA,cur);
  scan1<<<NODES/256,256,0,stream>>>(cur,rp,bsum);
  scan2<<<1,128,0,stream>>>(bsum,rp);
  scan3<<<NODES/256,256,0,stream>>>(rp,bsum);
  hipMemsetAsync(cur,0,NODES*sizeof(u32),stream);
  scatter_edges<<<NE/256,256,0,stream>>>(srcA,dstA,et,rp,cur,adj);

  // layer 0
  phase_a<<<NODES/4,256,0,stream>>>(x0,adj,rp,S);
  layer_gemm<<<NODES/64,256,0,stream>>>(x0,S,rW,sW,sb,rp,mask,x1,0);
  // layer 1
  phase_a<<<NODES/4,256,0,stream>>>(x1,adj,rp,S);
  layer_gemm<<<NODES/64,256,0,stream>>>(x1,S,rW+(size_t)NR*HD*HD,sW+(size_t)HD*HD,sb+HD,rp,mask,out,1);
}

// Round 2
// 436.614 us; speedup vs baseline: 1.3064x; 1.3064x over previous
//
#include <hip/hip_runtime.h>
#include <hip/hip_bf16.h>

#define NODES 32768
#define HD 128
#define NE 524288
#define NR 8

typedef unsigned int u32;
typedef unsigned short u16;
typedef __attribute__((ext_vector_type(8))) short bf16x8;
typedef __attribute__((ext_vector_type(4))) float f32x4;

// ---- ws byte offsets ----
#define XH0_OFF  (0u)
#define XL0_OFF  (8u<<20)
#define XH1_OFF  (16u<<20)
#define XL1_OFF  (24u<<20)
#define S_OFF    (32u<<20)                 // bf16, 64 MB (prescaled by 1/deg)
#define ADJ_OFF  (96u<<20)                 // u32 x NE
#define RP_OFF   (98u<<20)                 // u32 x (NODES+1)
#define CUR_OFF  ((98u<<20)+(256u<<10))    // u32 x NODES
#define BSUM_OFF ((98u<<20)+(512u<<10))    // u32 x 128
#define BP_OFF   ((98u<<20)+(640u<<10))    // packed weights bf16, 2 layers x 294912 elems

// per-layer packed-B element offsets
#define BM_HI 0
#define BM_LO 131072
#define BS_HI 262144
#define BS_LO 278528
#define BP_LAYER 294912

__device__ __forceinline__ float bflo(u32 u){ union{u32 i;float f;}c; c.i=u<<16; return c.f; }
__device__ __forceinline__ float bfhi(u32 u){ union{u32 i;float f;}c; c.i=u&0xffff0000u; return c.f; }
__device__ __forceinline__ u16 f2bf(float f){
  u32 u=__float_as_uint(f);
  u32 r=u + 0x7fffu + ((u>>16)&1u);
  return (u16)(r>>16);
}
__device__ __forceinline__ float bf2f(u16 h){ return __uint_as_float(((u32)h)<<16); }

__device__ __forceinline__ void gl_lds16(const void* g, void* l){
  __builtin_amdgcn_global_load_lds((const __attribute__((address_space(1))) u32*)g,
                                   (__attribute__((address_space(3))) u32*)l, 16, 0, 0);
}

// ---------------- embed + projection GEMM (fp32 vector): x0 = (cemb[cid]+kemb[kid]) @ pW^T + pb
__device__ __forceinline__ void fma64(const float* At, const float* Wt,
                                      int mq, int gq, float acc[8][4])
{
#pragma unroll 8
  for(int kk=0;kk<64;kk++){
    const float4 a0=*(const float4*)&At[kk*68+mq*8];
    const float4 a1=*(const float4*)&At[kk*68+mq*8+4];
    const float4 w =*(const float4*)&Wt[kk*132+gq*4];
    float av[8]={a0.x,a0.y,a0.z,a0.w,a1.x,a1.y,a1.z,a1.w};
#pragma unroll
    for(int i=0;i<8;i++){
      acc[i][0]=fmaf(av[i],w.x,acc[i][0]);
      acc[i][1]=fmaf(av[i],w.y,acc[i][1]);
      acc[i][2]=fmaf(av[i],w.z,acc[i][2]);
      acc[i][3]=fmaf(av[i],w.w,acc[i][3]);
    }
  }
}

__global__ __launch_bounds__(256) void embed_gemm(
    const int* __restrict__ cid, const int* __restrict__ kid,
    const float* __restrict__ cemb, const float* __restrict__ kemb,
    const float* __restrict__ pW, const float* __restrict__ pb,
    u16* __restrict__ xh, u16* __restrict__ xl)
{
  __shared__ float At[64*68];
  __shared__ float Wt[64*132];
  const int tid=threadIdx.x;
  const int d0=blockIdx.x*64;
  const int mq=tid>>5, gq=tid&31;
  float acc[8][4];
#pragma unroll
  for(int i=0;i<8;i++){ acc[i][0]=0.f; acc[i][1]=0.f; acc[i][2]=0.f; acc[i][3]=0.f; }

  for(int c=0;c<2;c++){
    const int h0=c*64;
    __syncthreads();
    { int m=tid>>2; int hh=(tid&3)*16;
      int ci=cid[d0+m], ki=kid[d0+m];
      const float* cp=cemb+(size_t)ci*HD+h0+hh;
      const float* kp=kemb+(size_t)ki*HD+h0+hh;
      float* ap=&At[hh*68+m];
#pragma unroll
      for(int j=0;j<16;j+=4){
        float4 a=*(const float4*)(cp+j);
        float4 b=*(const float4*)(kp+j);
        ap[(j+0)*68]=a.x+b.x; ap[(j+1)*68]=a.y+b.y;
        ap[(j+2)*68]=a.z+b.z; ap[(j+3)*68]=a.w+b.w;
      }
    }
    { int g=tid>>1; int hh=(tid&1)*32;
      const float* wp=pW+(size_t)g*HD+h0+hh;
      float* wl=&Wt[hh*132+g];
#pragma unroll
      for(int j=0;j<32;j+=4){
        float4 w=*(const float4*)(wp+j);
        wl[(j+0)*132]=w.x; wl[(j+1)*132]=w.y; wl[(j+2)*132]=w.z; wl[(j+3)*132]=w.w;
      }
    }
    __syncthreads();
    fma64(At,Wt,mq,gq,acc);
  }
  const float4 bias=*(const float4*)&pb[gq*4];
#pragma unroll
  for(int i=0;i<8;i++){
    int m=d0+mq*8+i;
    float v[4]={acc[i][0]+bias.x,acc[i][1]+bias.y,acc[i][2]+bias.z,acc[i][3]+bias.w};
    u16 hb[4], lb[4];
#pragma unroll
    for(int j=0;j<4;j++){ hb[j]=f2bf(v[j]); lb[j]=f2bf(v[j]-bf2f(hb[j])); }
    uint2 hv={(u32)hb[0]|((u32)hb[1]<<16),(u32)hb[2]|((u32)hb[3]<<16)};
    uint2 lv={(u32)lb[0]|((u32)lb[1]<<16),(u32)lb[2]|((u32)lb[3]<<16)};
    *(uint2*)&xh[(size_t)m*HD+gq*4]=hv;
    *(uint2*)&xl[(size_t)m*HD+gq*4]=lv;
  }
}

// ---------------- weight prep: split fp32 W into bf16 hi/lo, MFMA-fragment-contiguous layout
// B element (k,n): k = kc*64 + ks*32 + q*8 + j  ->  offset ((kc*2+ks)*128+n)*32 + q*8 + j
__global__ void prep_w(const float* __restrict__ rW, const float* __restrict__ sW,
                       u16* __restrict__ Bp)
{
  int idx=blockIdx.x*256+threadIdx.x;           // 2*1152*128 total
  int l=idx/(1152*128);
  int rem=idx%(1152*128);
  int k=rem>>7, n=rem&127;
  u16* base=Bp+(size_t)l*BP_LAYER;
  float w; size_t dst; size_t lodelta;
  if(k<1024){
    int r=k>>7, h=k&127;
    w=rW[((size_t)l*NR+r)*16384 + (size_t)n*HD + h];
    int kc=k>>6, kin=k&63, ks=kin>>5, q=(kin>>3)&3, j=kin&7;
    dst=BM_HI + ((size_t)(kc*2+ks)*128+n)*32 + q*8 + j;
    lodelta=BM_LO-BM_HI;
  } else {
    int h=k-1024;
    w=sW[(size_t)l*16384 + (size_t)n*HD + h];
    int kc=h>>6, kin=h&63, ks=kin>>5, q=(kin>>3)&3, j=kin&7;
    dst=BS_HI + ((size_t)(kc*2+ks)*128+n)*32 + q*8 + j;
    lodelta=BS_LO-BS_HI;
  }
  u16 hb=f2bf(w);
  u16 lb=f2bf(w-bf2f(hb));
  base[dst]=hb;
  base[dst+lodelta]=lb;
}

// ---------------- CSR build ----------------
__global__ void count_deg(const int* __restrict__ dst, u32* __restrict__ cnt){
  int e=blockIdx.x*256+threadIdx.x;
  atomicAdd(&cnt[dst[e]],1u);
}

__global__ void scan1(const u32* __restrict__ cnt, u32* __restrict__ rp, u32* __restrict__ bsum){
  __shared__ u32 sh[256];
  int t=threadIdx.x; int base=blockIdx.x*256;
  u32 v=cnt[base+t]; sh[t]=v; __syncthreads();
  for(int off=1;off<256;off<<=1){
    u32 tv=(t>=off)?sh[t-off]:0u; __syncthreads();
    sh[t]+=tv; __syncthreads();
  }
  rp[base+t]=sh[t]-v;
  if(t==255) bsum[blockIdx.x]=sh[255];
}

__global__ void scan2(u32* __restrict__ bsum, u32* __restrict__ rp){
  __shared__ u32 sh[128];
  int t=threadIdx.x;
  u32 v=bsum[t]; sh[t]=v; __syncthreads();
  for(int off=1;off<128;off<<=1){
    u32 tv=(t>=off)?sh[t-off]:0u; __syncthreads();
    sh[t]+=tv; __syncthreads();
  }
  bsum[t]=sh[t]-v;
  if(t==0) rp[NODES]=NE;
}

__global__ void scan3(u32* __restrict__ rp, const u32* __restrict__ bsum){
  int i=blockIdx.x*256+threadIdx.x;
  rp[i]+=bsum[blockIdx.x];
}

__global__ void scatter_edges(const int* __restrict__ src, const int* __restrict__ dst,
                              const int* __restrict__ et, const u32* __restrict__ rp,
                              u32* __restrict__ cur, u32* __restrict__ adj){
  int e=blockIdx.x*256+threadIdx.x;
  int d=dst[e];
  u32 pos=atomicAdd(&cur[d],1u);
  adj[rp[d]+pos]=(u32)src[e] | ((u32)et[e]<<16);
}

// ---------------- phase A: S[d][r][:] = (1/deg) * sum of x[src] over in-edges of type r
__global__ __launch_bounds__(256) void phase_a(
    const u16* __restrict__ xh, const u16* __restrict__ xl,
    const u32* __restrict__ adj, const u32* __restrict__ rp,
    u16* __restrict__ S)
{
  __shared__ float sacc[4][NR*HD];
  const int w=threadIdx.x>>6, lane=threadIdx.x&63;
  const int d=blockIdx.x*4+w;
  for(int i=lane;i<NR*HD;i+=64) sacc[w][i]=0.f;
  __syncthreads();
  const int beg=(int)rp[d], end=(int)rp[d+1];
  for(int e=beg;e<end;++e){
    u32 a=adj[e];
    int srcn=(int)(a&0xffffu); int t=(int)(a>>16);
    u32 h=*(const u32*)&xh[(size_t)srcn*HD+2*lane];
    u32 l=*(const u32*)&xl[(size_t)srcn*HD+2*lane];
    float f0=bflo(h)+bflo(l);
    float f1=bfhi(h)+bfhi(l);
    float* p=&sacc[w][t*HD+2*lane];
    p[0]+=f0; p[1]+=f1;
  }
  __syncthreads();
  float inv=1.f/fmaxf((float)(end-beg),1.f);
  u16* so=S+(size_t)d*(NR*HD);
  for(int i=0;i<16;i++){
    int k=i*64+lane;
    so[k]=f2bf(sacc[w][k]*inv);
  }
}

// ---------------- layer MFMA GEMM ----------------
// C[m][n] = relu( S[m]@(Whi+Wlo) + xhi[m]@(sWhi+sWlo) + xlo[m]@sWhi + b[n] ) [* mask]
// block: 128 rows x 128 cols, 4 waves in 2x2, each wave 64x64 via 4x4 16x16x32 MFMAs
__global__ __launch_bounds__(256) void layer_mfma(
    const u16* __restrict__ S, const u16* __restrict__ xhi, const u16* __restrict__ xlo,
    const u16* __restrict__ Bp, const float* __restrict__ selfb,
    const int* __restrict__ mask,
    u16* __restrict__ outhi, u16* __restrict__ outlo, float* __restrict__ outf, int last)
{
  __shared__ u16 Atile[128*64];   // 16 KB, row-major 128B rows, 16B-chunk XOR swizzle
  const int tid=threadIdx.x;
  const int wave=tid>>6, lane=tid&63;
  const int wm=wave>>1, wn=wave&1;
  const int q=lane>>4;
  const int d0=blockIdx.x*128;

  f32x4 acc[4][4];
#pragma unroll
  for(int a=0;a<4;a++)
#pragma unroll
    for(int b=0;b<4;b++) acc[a][b]=(f32x4){0.f,0.f,0.f,0.f};

  // staging lane geometry: wave covers rows wave*32 .. +32, 4 issues of 8 rows
  const int st_row_in = lane>>3;               // 0..7 within an 8-row issue
  const int st_gj = (lane&7) ^ (lane>>3);      // swizzled source 16B-chunk

#define STAGE(SRC, RSTRIDE, C0) do {                                        \
    _Pragma("unroll")                                                       \
    for(int i_=0;i_<4;i_++){                                                \
      int r_=wave*32+i_*8+st_row_in;                                        \
      const u16* g_=(SRC)+(size_t)(d0+r_)*(RSTRIDE)+(C0)+st_gj*8;           \
      gl_lds16(g_, &Atile[(wave*32+i_*8)*64]);                              \
    }                                                                       \
  } while(0)

  // ---- phase 1: S chunks (K=1024), B segs {Bm_hi, Bm_lo} reuse staged A ----
  for(int c=0;c<16;c++){
    __syncthreads();
    STAGE(S, 1024, c*64);
    __syncthreads();
    bf16x8 afr[2][4];
#pragma unroll
    for(int ks=0;ks<2;ks++)
#pragma unroll
      for(int tm=0;tm<4;tm++){
        int m=wm*64+tm*16+(lane&15);
        afr[ks][tm]=*(const bf16x8*)&Atile[m*64+(((ks*4)+q)^(m&7))*8];
      }
#pragma unroll
    for(int s=0;s<2;s++){
      const u16* Bb=Bp + (s? BM_LO: BM_HI);
#pragma unroll
      for(int ks=0;ks<2;ks++){
#pragma unroll
        for(int tn=0;tn<4;tn++){
          int n=wn*64+tn*16+(lane&15);
          bf16x8 bfr=*(const bf16x8*)&Bb[((size_t)(c*2+ks)*128+n)*32+q*8];
#pragma unroll
          for(int tm=0;tm<4;tm++)
            acc[tm][tn]=__builtin_amdgcn_mfma_f32_16x16x32_bf16(afr[ks][tm],bfr,acc[tm][tn],0,0,0);
        }
      }
    }
  }

  // ---- phase 2: xhi (segs {Bs_hi,Bs_lo}), then xlo (seg {Bs_hi}) ----
#pragma unroll
  for(int part=0;part<2;part++){
    const u16* xs = part? xlo : xhi;
    const int nseg = part? 1 : 2;
    for(int c=0;c<2;c++){
      __syncthreads();
      STAGE(xs, 128, c*64);
      __syncthreads();
      bf16x8 afr[2][4];
#pragma unroll
      for(int ks=0;ks<2;ks++)
#pragma unroll
        for(int tm=0;tm<4;tm++){
          int m=wm*64+tm*16+(lane&15);
          afr[ks][tm]=*(const bf16x8*)&Atile[m*64+(((ks*4)+q)^(m&7))*8];
        }
      for(int s=0;s<nseg;s++){
        const u16* Bb=Bp + (s? BS_LO: BS_HI);
#pragma unroll
        for(int ks=0;ks<2;ks++){
#pragma unroll
          for(int tn=0;tn<4;tn++){
            int n=wn*64+tn*16+(lane&15);
            bf16x8 bfr=*(const bf16x8*)&Bb[((size_t)(c*2+ks)*128+n)*32+q*8];
#pragma unroll
            for(int tm=0;tm<4;tm++)
              acc[tm][tn]=__builtin_amdgcn_mfma_f32_16x16x32_bf16(afr[ks][tm],bfr,acc[tm][tn],0,0,0);
          }
        }
      }
    }
  }
#undef STAGE

  // ---- epilogue: C/D layout col=lane&15, row=(lane>>4)*4+reg ----
#pragma unroll
  for(int tn=0;tn<4;tn++){
    int n=wn*64+tn*16+(lane&15);
    float b=selfb[n];
#pragma unroll
    for(int tm=0;tm<4;tm++){
      int rbase=d0+wm*64+tm*16+q*4;
#pragma unroll
      for(int r=0;r<4;r++){
        float v=fmaxf(acc[tm][tn][r]+b,0.f);
        int m=rbase+r;
        if(last){
          v*=(float)mask[m];
          outf[(size_t)m*HD+n]=v;
        } else {
          u16 hb=f2bf(v);
          u16 lb=f2bf(v-bf2f(hb));
          outhi[(size_t)m*HD+n]=hb;
          outlo[(size_t)m*HD+n]=lb;
        }
      }
    }
  }
}

extern "C" void kernel_launch(void* const* d_in, const int* in_sizes, int n_in,
                              void* d_out, int out_size, void* d_ws, size_t ws_size,
                              hipStream_t stream)
{
  (void)in_sizes; (void)n_in; (void)out_size; (void)ws_size;
  const int*   cid =(const int*)  d_in[0];
  const int*   kid =(const int*)  d_in[1];
  const int*   mask=(const int*)  d_in[2];
  const int*   ei  =(const int*)  d_in[3];
  const int*   et  =(const int*)  d_in[4];
  const float* cemb=(const float*)d_in[5];
  const float* kemb=(const float*)d_in[6];
  const float* pW  =(const float*)d_in[7];
  const float* pb  =(const float*)d_in[8];
  const float* sW  =(const float*)d_in[9];
  const float* sb  =(const float*)d_in[10];
  const float* rW  =(const float*)d_in[11];
  float* out=(float*)d_out;
  char*  ws =(char*)d_ws;

  u16* xh0=(u16*)(ws+XH0_OFF);
  u16* xl0=(u16*)(ws+XL0_OFF);
  u16* xh1=(u16*)(ws+XH1_OFF);
  u16* xl1=(u16*)(ws+XL1_OFF);
  u16* S  =(u16*)(ws+S_OFF);
  u32* adj =(u32*)(ws+ADJ_OFF);
  u32* rp  =(u32*)(ws+RP_OFF);
  u32* cur =(u32*)(ws+CUR_OFF);
  u32* bsum=(u32*)(ws+BSUM_OFF);
  u16* Bp  =(u16*)(ws+BP_OFF);
  const int* srcA=ei;
  const int* dstA=ei+NE;

  hipMemsetAsync(cur,0,NODES*sizeof(u32),stream);
  prep_w<<<1152,256,0,stream>>>(rW,sW,Bp);
  embed_gemm<<<NODES/64,256,0,stream>>>(cid,kid,cemb,kemb,pW,pb,xh0,xl0);
  count_deg<<<NE/256,256,0,stream>>>(dstA,cur);
  scan1<<<NODES/256,256,0,stream>>>(cur,rp,bsum);
  scan2<<<1,128,0,stream>>>(bsum,rp);
  scan3<<<NODES/256,256,0,stream>>>(rp,bsum);
  hipMemsetAsync(cur,0,NODES*sizeof(u32),stream);
  scatter_edges<<<NE/256,256,0,stream>>>(srcA,dstA,et,rp,cur,adj);

  // layer 0
  phase_a<<<NODES/4,256,0,stream>>>(xh0,xl0,adj,rp,S);
  layer_mfma<<<NODES/128,256,0,stream>>>(S,xh0,xl0,Bp,sb,mask,xh1,xl1,out,0);
  // layer 1
  phase_a<<<NODES/4,256,0,stream>>>(xh1,xl1,adj,rp,S);
  layer_mfma<<<NODES/128,256,0,stream>>>(S,xh1,xl1,Bp+BP_LAYER,sb+HD,mask,xh1,xl1,out,1);
}

// Round 3
// 360.925 us; speedup vs baseline: 1.5804x; 1.2097x over previous
//
#include <hip/hip_runtime.h>
#include <hip/hip_bf16.h>

#define NODES 32768
#define HD 128
#define NE 524288
#define NR 8

typedef unsigned int u32;
typedef unsigned short u16;
typedef __attribute__((ext_vector_type(8))) short bf16x8;
typedef __attribute__((ext_vector_type(4))) float f32x4;

// ---- ws byte offsets ----
#define XH_OFF   (0u)                      // bf16 hi, 8 MB (reused both layers)
#define XL_OFF   (8u<<20)                  // bf16 lo, 8 MB
#define Y_OFF    (16u<<20)                 // bf16 y[8][NODES][128], 64 MB
#define Z_OFF    (80u<<20)                 // fp32 z[NODES][128], 16 MB
#define ADJ_OFF  (96u<<20)                 // u32 x NE
#define RP_OFF   (98u<<20)                 // u32 x (NODES+1)
#define CUR_OFF  ((98u<<20)+(256u<<10))    // u32 x NODES
#define BSUM_OFF ((98u<<20)+(512u<<10))    // u32 x 128
#define BP_OFF   ((98u<<20)+(640u<<10))    // packed weights bf16: 2 layers x 9 tiles x 2 segs x 16384

#define BP_LAYER 294912                    // 9*2*16384

__device__ __forceinline__ float bflo(u32 u){ union{u32 i;float f;}c; c.i=u<<16; return c.f; }
__device__ __forceinline__ float bfhi(u32 u){ union{u32 i;float f;}c; c.i=u&0xffff0000u; return c.f; }
__device__ __forceinline__ u16 f2bf(float f){
  u32 u=__float_as_uint(f);
  u32 r=u + 0x7fffu + ((u>>16)&1u);
  return (u16)(r>>16);
}
__device__ __forceinline__ float bf2f(u16 h){ return __uint_as_float(((u32)h)<<16); }

__device__ __forceinline__ void gl_lds16(const void* g, void* l){
  __builtin_amdgcn_global_load_lds((const __attribute__((address_space(1))) u32*)g,
                                   (__attribute__((address_space(3))) u32*)l, 16, 0, 0);
}

// ---------------- embed + projection GEMM (fp32 vector) ----------------
__device__ __forceinline__ void fma64(const float* At, const float* Wt,
                                      int mq, int gq, float acc[8][4])
{
#pragma unroll 8
  for(int kk=0;kk<64;kk++){
    const float4 a0=*(const float4*)&At[kk*68+mq*8];
    const float4 a1=*(const float4*)&At[kk*68+mq*8+4];
    const float4 w =*(const float4*)&Wt[kk*132+gq*4];
    float av[8]={a0.x,a0.y,a0.z,a0.w,a1.x,a1.y,a1.z,a1.w};
#pragma unroll
    for(int i=0;i<8;i++){
      acc[i][0]=fmaf(av[i],w.x,acc[i][0]);
      acc[i][1]=fmaf(av[i],w.y,acc[i][1]);
      acc[i][2]=fmaf(av[i],w.z,acc[i][2]);
      acc[i][3]=fmaf(av[i],w.w,acc[i][3]);
    }
  }
}

__global__ __launch_bounds__(256) void embed_gemm(
    const int* __restrict__ cid, const int* __restrict__ kid,
    const float* __restrict__ cemb, const float* __restrict__ kemb,
    const float* __restrict__ pW, const float* __restrict__ pb,
    u16* __restrict__ xh, u16* __restrict__ xl)
{
  __shared__ float At[64*68];
  __shared__ float Wt[64*132];
  const int tid=threadIdx.x;
  const int d0=blockIdx.x*64;
  const int mq=tid>>5, gq=tid&31;
  float acc[8][4];
#pragma unroll
  for(int i=0;i<8;i++){ acc[i][0]=0.f; acc[i][1]=0.f; acc[i][2]=0.f; acc[i][3]=0.f; }

  for(int c=0;c<2;c++){
    const int h0=c*64;
    __syncthreads();
    { int m=tid>>2; int hh=(tid&3)*16;
      int ci=cid[d0+m], ki=kid[d0+m];
      const float* cp=cemb+(size_t)ci*HD+h0+hh;
      const float* kp=kemb+(size_t)ki*HD+h0+hh;
      float* ap=&At[hh*68+m];
#pragma unroll
      for(int j=0;j<16;j+=4){
        float4 a=*(const float4*)(cp+j);
        float4 b=*(const float4*)(kp+j);
        ap[(j+0)*68]=a.x+b.x; ap[(j+1)*68]=a.y+b.y;
        ap[(j+2)*68]=a.z+b.z; ap[(j+3)*68]=a.w+b.w;
      }
    }
    { int g=tid>>1; int hh=(tid&1)*32;
      const float* wp=pW+(size_t)g*HD+h0+hh;
      float* wl=&Wt[hh*132+g];
#pragma unroll
      for(int j=0;j<32;j+=4){
        float4 w=*(const float4*)(wp+j);
        wl[(j+0)*132]=w.x; wl[(j+1)*132]=w.y; wl[(j+2)*132]=w.z; wl[(j+3)*132]=w.w;
      }
    }
    __syncthreads();
    fma64(At,Wt,mq,gq,acc);
  }
  const float4 bias=*(const float4*)&pb[gq*4];
#pragma unroll
  for(int i=0;i<8;i++){
    int m=d0+mq*8+i;
    float v[4]={acc[i][0]+bias.x,acc[i][1]+bias.y,acc[i][2]+bias.z,acc[i][3]+bias.w};
    u16 hb[4], lb[4];
#pragma unroll
    for(int j=0;j<4;j++){ hb[j]=f2bf(v[j]); lb[j]=f2bf(v[j]-bf2f(hb[j])); }
    uint2 hv={(u32)hb[0]|((u32)hb[1]<<16),(u32)hb[2]|((u32)hb[3]<<16)};
    uint2 lv={(u32)lb[0]|((u32)lb[1]<<16),(u32)lb[2]|((u32)lb[3]<<16)};
    *(uint2*)&xh[(size_t)m*HD+gq*4]=hv;
    *(uint2*)&xl[(size_t)m*HD+gq*4]=lv;
  }
}

// ---------------- weight prep: per layer, 9 n-tiles (8 relations + self), hi/lo segs,
// MFMA-fragment-contiguous: k = kc*64 + ks*32 + q*8 + j -> ((kc*2+ks)*128+n)*32 + q*8 + j
__global__ void prep_w(const float* __restrict__ rW, const float* __restrict__ sW,
                       u16* __restrict__ Bp)
{
  int idx=blockIdx.x*256+threadIdx.x;           // 2 * 9 * 16384 = 294912 total
  int l=idx/147456;
  int rem=idx%147456;
  int t=rem>>14;
  int kn=rem&16383;
  int k=kn>>7, n=kn&127;
  float w;
  if(t<8) w=rW[(((size_t)l*NR+t)*HD+n)*HD+k];
  else    w=sW[((size_t)l*HD+n)*HD+k];
  u16* base=Bp+(size_t)l*BP_LAYER+(size_t)t*32768;
  int kc=k>>6, kin=k&63, ks=kin>>5, q=(kin>>3)&3, j=kin&7;
  size_t off=((size_t)(kc*2+ks)*128+n)*32+q*8+j;
  u16 hb=f2bf(w);
  u16 lb=f2bf(w-bf2f(hb));
  base[off]=hb;
  base[off+16384]=lb;
}

// ---------------- CSR build ----------------
__global__ void count_deg(const int* __restrict__ dst, u32* __restrict__ cnt){
  int e=blockIdx.x*256+threadIdx.x;
  atomicAdd(&cnt[dst[e]],1u);
}

__global__ void scan1(const u32* __restrict__ cnt, u32* __restrict__ rp, u32* __restrict__ bsum){
  __shared__ u32 sh[256];
  int t=threadIdx.x; int base=blockIdx.x*256;
  u32 v=cnt[base+t]; sh[t]=v; __syncthreads();
  for(int off=1;off<256;off<<=1){
    u32 tv=(t>=off)?sh[t-off]:0u; __syncthreads();
    sh[t]+=tv; __syncthreads();
  }
  rp[base+t]=sh[t]-v;
  if(t==255) bsum[blockIdx.x]=sh[255];
}

__global__ void scan2(u32* __restrict__ bsum, u32* __restrict__ rp){
  __shared__ u32 sh[128];
  int t=threadIdx.x;
  u32 v=bsum[t]; sh[t]=v; __syncthreads();
  for(int off=1;off<128;off<<=1){
    u32 tv=(t>=off)?sh[t-off]:0u; __syncthreads();
    sh[t]+=tv; __syncthreads();
  }
  bsum[t]=sh[t]-v;
  if(t==0) rp[NODES]=NE;
}

__global__ void scan3(u32* __restrict__ rp, const u32* __restrict__ bsum){
  int i=blockIdx.x*256+threadIdx.x;
  rp[i]+=bsum[blockIdx.x];
}

__global__ void scatter_edges(const int* __restrict__ src, const int* __restrict__ dst,
                              const int* __restrict__ et, const u32* __restrict__ rp,
                              u32* __restrict__ cur, u32* __restrict__ adj){
  int e=blockIdx.x*256+threadIdx.x;
  int d=dst[e];
  u32 pos=atomicAdd(&cur[d],1u);
  adj[rp[d]+pos]=(u32)src[e] | ((u32)et[e]<<16);
}

// ---------------- gemm_y: y[t] = x @ W_t^T (t<8, bf16 out), z = x @ selfW^T (t==8, fp32 out)
// 128x128 tile per block, grid (NODES/128, 9); hi/lo split: xhi*(Bhi+Blo) + xlo*Bhi
__global__ __launch_bounds__(256) void gemm_y(
    const u16* __restrict__ xhi, const u16* __restrict__ xlo,
    const u16* __restrict__ Bt, u16* __restrict__ y, float* __restrict__ z)
{
  __shared__ u16 Atile[128*64];   // 16 KB, 128B rows, 16B-chunk XOR swizzle
  const int tid=threadIdx.x;
  const int wave=tid>>6, lane=tid&63;
  const int wm=wave>>1, wn=wave&1;
  const int q=lane>>4;
  const int d0=blockIdx.x*128;
  const int t=blockIdx.y;
  const u16* Btile=Bt+(size_t)t*32768;

  f32x4 acc[4][4];
#pragma unroll
  for(int a=0;a<4;a++)
#pragma unroll
    for(int b=0;b<4;b++) acc[a][b]=(f32x4){0.f,0.f,0.f,0.f};

  const int st_row_in = lane>>3;
  const int st_gj = (lane&7) ^ (lane>>3);

#pragma unroll
  for(int part=0;part<2;part++){
    const u16* xs = part? xlo : xhi;
    const int nseg = part? 1 : 2;
    for(int c=0;c<2;c++){
      __syncthreads();
#pragma unroll
      for(int i_=0;i_<4;i_++){
        int r_=wave*32+i_*8+st_row_in;
        const u16* g_=xs+(size_t)(d0+r_)*HD+c*64+st_gj*8;
        gl_lds16(g_, &Atile[(wave*32+i_*8)*64]);
      }
      __syncthreads();
      bf16x8 afr[2][4];
#pragma unroll
      for(int ks=0;ks<2;ks++)
#pragma unroll
        for(int tm=0;tm<4;tm++){
          int m=wm*64+tm*16+(lane&15);
          afr[ks][tm]=*(const bf16x8*)&Atile[m*64+(((ks*4)+q)^(m&7))*8];
        }
      for(int s=0;s<nseg;s++){
        const u16* Bb=Btile + s*16384;
#pragma unroll
        for(int ks=0;ks<2;ks++){
#pragma unroll
          for(int tn=0;tn<4;tn++){
            int n=wn*64+tn*16+(lane&15);
            bf16x8 bfr=*(const bf16x8*)&Bb[((size_t)(c*2+ks)*128+n)*32+q*8];
#pragma unroll
            for(int tm=0;tm<4;tm++)
              acc[tm][tn]=__builtin_amdgcn_mfma_f32_16x16x32_bf16(afr[ks][tm],bfr,acc[tm][tn],0,0,0);
          }
        }
      }
    }
  }

  // epilogue: C/D layout col=lane&15, row=(lane>>4)*4+reg
#pragma unroll
  for(int tn=0;tn<4;tn++){
    int n=wn*64+tn*16+(lane&15);
#pragma unroll
    for(int tm=0;tm<4;tm++){
      int rbase=d0+wm*64+tm*16+q*4;
#pragma unroll
      for(int r=0;r<4;r++){
        int m=rbase+r;
        if(t<8) y[((size_t)t*NODES+m)*HD+n]=f2bf(acc[tm][tn][r]);
        else    z[(size_t)m*HD+n]=acc[tm][tn][r];
      }
    }
  }
}

// ---------------- gather_combine: agg = (1/deg) * sum_e y[type][src]; out = relu(z+agg+b)
__global__ __launch_bounds__(256) void gather_combine(
    const u32* __restrict__ y, const float* __restrict__ z,
    const u32* __restrict__ adj, const u32* __restrict__ rp,
    const float* __restrict__ sb, const int* __restrict__ mask,
    u32* __restrict__ xh, u32* __restrict__ xl, float* __restrict__ outf, int last)
{
  const int wave=threadIdx.x>>6, lane=threadIdx.x&63;
  const int node=blockIdx.x*4+wave;
  const int beg=(int)rp[node], end=(int)rp[node+1];
  float a0=0.f, a1=0.f;
  int e=beg;
  for(; e+4<=end; e+=4){
    u32 q0=adj[e], q1=adj[e+1], q2=adj[e+2], q3=adj[e+3];
    u32 v0=y[((size_t)(q0>>16)*NODES+(q0&0x7fffu))*64+lane];
    u32 v1=y[((size_t)(q1>>16)*NODES+(q1&0x7fffu))*64+lane];
    u32 v2=y[((size_t)(q2>>16)*NODES+(q2&0x7fffu))*64+lane];
    u32 v3=y[((size_t)(q3>>16)*NODES+(q3&0x7fffu))*64+lane];
    a0+=bflo(v0)+bflo(v1)+bflo(v2)+bflo(v3);
    a1+=bfhi(v0)+bfhi(v1)+bfhi(v2)+bfhi(v3);
  }
  for(; e<end; ++e){
    u32 qq=adj[e];
    u32 v=y[((size_t)(qq>>16)*NODES+(qq&0x7fffu))*64+lane];
    a0+=bflo(v); a1+=bfhi(v);
  }
  float inv=1.f/fmaxf((float)(end-beg),1.f);
  float2 zz=*(const float2*)&z[(size_t)node*HD+2*lane];
  float2 bb=*(const float2*)&sb[2*lane];
  float v0=fmaxf(zz.x+a0*inv+bb.x,0.f);
  float v1=fmaxf(zz.y+a1*inv+bb.y,0.f);
  if(last){
    float mk=(float)mask[node];
    float2 o={v0*mk,v1*mk};
    *(float2*)&outf[(size_t)node*HD+2*lane]=o;
  } else {
    u16 h0=f2bf(v0), h1=f2bf(v1);
    u16 l0=f2bf(v0-bf2f(h0)), l1=f2bf(v1-bf2f(h1));
    xh[(size_t)node*64+lane]=(u32)h0|((u32)h1<<16);
    xl[(size_t)node*64+lane]=(u32)l0|((u32)l1<<16);
  }
}

extern "C" void kernel_launch(void* const* d_in, const int* in_sizes, int n_in,
                              void* d_out, int out_size, void* d_ws, size_t ws_size,
                              hipStream_t stream)
{
  (void)in_sizes; (void)n_in; (void)out_size; (void)ws_size;
  const int*   cid =(const int*)  d_in[0];
  const int*   kid =(const int*)  d_in[1];
  const int*   mask=(const int*)  d_in[2];
  const int*   ei  =(const int*)  d_in[3];
  const int*   et  =(const int*)  d_in[4];
  const float* cemb=(const float*)d_in[5];
  const float* kemb=(const float*)d_in[6];
  const float* pW  =(const float*)d_in[7];
  const float* pb  =(const float*)d_in[8];
  const float* sW  =(const float*)d_in[9];
  const float* sb  =(const float*)d_in[10];
  const float* rW  =(const float*)d_in[11];
  float* out=(float*)d_out;
  char*  ws =(char*)d_ws;

  u16* xh =(u16*)(ws+XH_OFF);
  u16* xl =(u16*)(ws+XL_OFF);
  u16* y  =(u16*)(ws+Y_OFF);
  float* z=(float*)(ws+Z_OFF);
  u32* adj =(u32*)(ws+ADJ_OFF);
  u32* rp  =(u32*)(ws+RP_OFF);
  u32* cur =(u32*)(ws+CUR_OFF);
  u32* bsum=(u32*)(ws+BSUM_OFF);
  u16* Bp  =(u16*)(ws+BP_OFF);
  const int* srcA=ei;
  const int* dstA=ei+NE;

  hipMemsetAsync(cur,0,NODES*sizeof(u32),stream);
  prep_w<<<1152,256,0,stream>>>(rW,sW,Bp);
  embed_gemm<<<NODES/64,256,0,stream>>>(cid,kid,cemb,kemb,pW,pb,xh,xl);
  count_deg<<<NE/256,256,0,stream>>>(dstA,cur);
  scan1<<<NODES/256,256,0,stream>>>(cur,rp,bsum);
  scan2<<<1,128,0,stream>>>(bsum,rp);
  scan3<<<NODES/256,256,0,stream>>>(rp,bsum);
  hipMemsetAsync(cur,0,NODES*sizeof(u32),stream);
  scatter_edges<<<NE/256,256,0,stream>>>(srcA,dstA,et,rp,cur,adj);

  // layer 0
  gemm_y<<<dim3(NODES/128,9),256,0,stream>>>(xh,xl,Bp,y,z);
  gather_combine<<<NODES/4,256,0,stream>>>((const u32*)y,z,adj,rp,sb,mask,(u32*)xh,(u32*)xl,out,0);
  // layer 1
  gemm_y<<<dim3(NODES/128,9),256,0,stream>>>(xh,xl,Bp+BP_LAYER,y,z);
  gather_combine<<<NODES/4,256,0,stream>>>((const u32*)y,z,adj,rp,sb+HD,mask,(u32*)xh,(u32*)xl,out,1);
}